// Round 2
// 179.241 us; speedup vs baseline: 1.0858x; 1.0858x over previous
//
#include <hip/hip_runtime.h>
#include <hip/hip_bf16.h>

// ---------------------------------------------------------------------------
// Pipeline:
//  convert_split (X -> Xhi/Xlo bf16 planes)
//  gemm_mfma3 x3 (bf16 MFMA, hi/lo 3-split == near-fp32 accuracy, split-K)
//  reduce_ep x3  (sum partials + bias + lrelu; emits bf16 hi/lo planes)
//  gemm4_mfma (bf16 MFMA, K-split 4, bf16 accM)
//  pairwise -> feat[:,1024:]
//  final_dot
// ws layout (bytes):
//   [0, 10485760)          P (fp32 gemm partials, <=8.4MB) / accM bf16 4x128x10240
//   [10485760, 11010048)   Xhi  128x2048 bf16
//   [11010048, 11534336)   Xlo  128x2048 bf16
//   [11534336, 12058624)   h1hi 128x2048 bf16
//   [12058624, 12582912)   h1lo 128x2048 bf16
//   [12582912, 12845056)   h2hi 128x1024 bf16
//   [12845056, 13107200)   h2lo 128x1024 bf16
//   [13107200, 13369344)   h3hi 128x1024 bf16  (feeds gemm4)
//   [13369344, 14155776)   feat 128x1536 f32   ( [h3 | o_b] )
// ---------------------------------------------------------------------------

typedef __bf16 bf16x8 __attribute__((ext_vector_type(8)));
typedef __bf16 bf16x2 __attribute__((ext_vector_type(2)));
typedef float  f32x4  __attribute__((ext_vector_type(4)));

static __device__ __forceinline__ unsigned int f2bf(float f) {
  union { float f; unsigned int u; } v; v.f = f;
  unsigned int r = v.u + 0x7FFFu + ((v.u >> 16) & 1u);   // RNE to bf16
  return r >> 16;
}
static __device__ __forceinline__ float bf2f(unsigned short u) {
  union { unsigned int u; float f; } v; v.u = ((unsigned int)u) << 16;
  return v.f;
}
// packed RNE f32x2 -> bf16x2 (compiler emits v_cvt_pk_bf16_f32)
static __device__ __forceinline__ unsigned int pack_bf16_rne(float a, float b) {
  bf16x2 v; v[0] = (__bf16)a; v[1] = (__bf16)b;
  return __builtin_bit_cast(unsigned int, v);
}
static __device__ __forceinline__ float lrelu(float x) {
  return x >= 0.0f ? x : 0.01f * x;
}

// ---------------------------------------------------------------------------
// convert X fp32 -> hi/lo bf16 split planes.  x = hi + lo with err ~2^-17|x|.
// 128x2048 elems, 8 per thread -> 128 blocks x 256 thr.
// ---------------------------------------------------------------------------
__global__ __launch_bounds__(256) void convert_split(
    const float* __restrict__ X, unsigned short* __restrict__ Hi,
    unsigned short* __restrict__ Lo)
{
  const int g = blockIdx.x * 256 + threadIdx.x;
  float a[8];
  *(float4*)(a + 0) = *(const float4*)(X + (size_t)g * 8);
  *(float4*)(a + 4) = *(const float4*)(X + (size_t)g * 8 + 4);
  unsigned int hu[4], lu[4];
  #pragma unroll
  for (int i = 0; i < 4; i++) {
    float x0 = a[2 * i], x1 = a[2 * i + 1];
    unsigned int h = pack_bf16_rne(x0, x1);
    float f0 = bf2f((unsigned short)(h & 0xFFFFu));
    float f1 = bf2f((unsigned short)(h >> 16));
    hu[i] = h;
    lu[i] = pack_bf16_rne(x0 - f0, x1 - f1);
  }
  *(uint4*)(Hi + (size_t)g * 8) = *(uint4*)hu;
  *(uint4*)(Lo + (size_t)g * 8) = *(uint4*)lu;
}

// ---------------------------------------------------------------------------
// Dense-layer GEMM on matrix cores with hi/lo 3-split:
//   C = Ahi*Whi + Ahi*Wlo + Alo*Whi  (missing lo*lo term ~2^-18 rel)
// A given as pre-split bf16 planes [128][K]; W fp32 [K][N] converted in staging.
// Block 256 thr, tile 128x64, k-tile 32, split-K partials into P.
// A staging mirrors verified gemm4_mfma: ra=t>>2 (64 rows), qa=t&3 (8-ushort
// chunks), two row-halves -> full 128x32 coverage. Grid (N/64, S).
// ---------------------------------------------------------------------------
__global__ __launch_bounds__(256, 2) void gemm_mfma3(
    const unsigned short* __restrict__ Ahi, const unsigned short* __restrict__ Alo,
    const float* __restrict__ W, float* __restrict__ P,
    int K, int N, int kchunk)
{
  __shared__ __align__(16) unsigned short AHs[128 * 40];  // [row][k] pad 40
  __shared__ __align__(16) unsigned short ALs[128 * 40];
  __shared__ __align__(16) unsigned int   WHs[64 * 20];   // [n][kpair] pad 20
  __shared__ __align__(16) unsigned int   WLs[64 * 20];
  const int t     = threadIdx.x;
  const int c0    = blockIdx.x * 64;
  const int kbase = blockIdx.y * kchunk;
  const int lane  = t & 63, wave = t >> 6;
  const int ml    = lane & 15, q = lane >> 4;
  const int r0    = wave * 32;
  const int ra = t >> 2, qa = t & 3;            // A staging: 64 rows x 4 chunks
  const int kp = t & 15, n4 = (t >> 4) * 4;     // W staging

  f32x4 acc[2][4];
  #pragma unroll
  for (int i = 0; i < 2; i++)
    #pragma unroll
    for (int j = 0; j < 4; j++) acc[i][j] = (f32x4){0.f, 0.f, 0.f, 0.f};

  const unsigned short* ahp = Ahi + (size_t)ra * K + kbase + qa * 8;
  const unsigned short* alp = Alo + (size_t)ra * K + kbase + qa * 8;
  const float*          wp  = W + (size_t)(kbase + 2 * kp) * N + c0 + n4;
  uint4  vah0 = *(const uint4*)ahp;
  uint4  vah1 = *(const uint4*)(ahp + (size_t)64 * K);
  uint4  val0 = *(const uint4*)alp;
  uint4  val1 = *(const uint4*)(alp + (size_t)64 * K);
  float4 vw0 = *(const float4*)wp;
  float4 vw1 = *(const float4*)(wp + N);

  const int nkt = kchunk >> 5;
  for (int kt = 0; kt < nkt; kt++) {
    *(uint4*)(AHs + ra * 40 + qa * 8)        = vah0;
    *(uint4*)(AHs + (ra + 64) * 40 + qa * 8) = vah1;
    *(uint4*)(ALs + ra * 40 + qa * 8)        = val0;
    *(uint4*)(ALs + (ra + 64) * 40 + qa * 8) = val1;
    {
      float w0[4], w1[4];
      *(float4*)w0 = vw0; *(float4*)w1 = vw1;
      #pragma unroll
      for (int c = 0; c < 4; c++) {
        unsigned int hu = pack_bf16_rne(w0[c], w1[c]);
        float f0 = bf2f((unsigned short)(hu & 0xFFFFu));
        float f1 = bf2f((unsigned short)(hu >> 16));
        unsigned int lu = pack_bf16_rne(w0[c] - f0, w1[c] - f1);
        WHs[(n4 + c) * 20 + kp] = hu;
        WLs[(n4 + c) * 20 + kp] = lu;
      }
    }
    __syncthreads();
    if (kt + 1 < nkt) {                          // prefetch next k-tile
      ahp += 32; alp += 32;
      wp  += (size_t)32 * N;
      vah0 = *(const uint4*)ahp;
      vah1 = *(const uint4*)(ahp + (size_t)64 * K);
      val0 = *(const uint4*)alp;
      val1 = *(const uint4*)(alp + (size_t)64 * K);
      vw0 = *(const float4*)wp;
      vw1 = *(const float4*)(wp + N);
    }
    bf16x8 ah0 = *(const bf16x8*)(AHs + (r0 + ml) * 40 + q * 8);
    bf16x8 ah1 = *(const bf16x8*)(AHs + (r0 + 16 + ml) * 40 + q * 8);
    bf16x8 al0 = *(const bf16x8*)(ALs + (r0 + ml) * 40 + q * 8);
    bf16x8 al1 = *(const bf16x8*)(ALs + (r0 + 16 + ml) * 40 + q * 8);
    #pragma unroll
    for (int ct = 0; ct < 4; ct++) {
      bf16x8 bh = *(const bf16x8*)((const unsigned short*)WHs +
                                   (size_t)((ct * 16 + ml) * 20 + q * 4) * 2);
      bf16x8 bl = *(const bf16x8*)((const unsigned short*)WLs +
                                   (size_t)((ct * 16 + ml) * 20 + q * 4) * 2);
      acc[0][ct] = __builtin_amdgcn_mfma_f32_16x16x32_bf16(ah0, bh, acc[0][ct], 0, 0, 0);
      acc[1][ct] = __builtin_amdgcn_mfma_f32_16x16x32_bf16(ah1, bh, acc[1][ct], 0, 0, 0);
      acc[0][ct] = __builtin_amdgcn_mfma_f32_16x16x32_bf16(ah0, bl, acc[0][ct], 0, 0, 0);
      acc[1][ct] = __builtin_amdgcn_mfma_f32_16x16x32_bf16(ah1, bl, acc[1][ct], 0, 0, 0);
      acc[0][ct] = __builtin_amdgcn_mfma_f32_16x16x32_bf16(al0, bh, acc[0][ct], 0, 0, 0);
      acc[1][ct] = __builtin_amdgcn_mfma_f32_16x16x32_bf16(al1, bh, acc[1][ct], 0, 0, 0);
    }
    __syncthreads();
  }

  // C/D layout: col = lane&15, row = (lane>>4)*4 + reg
  float* op = P + (size_t)blockIdx.y * 128 * N;
  #pragma unroll
  for (int rt = 0; rt < 2; rt++)
    #pragma unroll
    for (int ct = 0; ct < 4; ct++) {
      const int col = c0 + ct * 16 + ml;
      const int row = r0 + rt * 16 + q * 4;
      #pragma unroll
      for (int i = 0; i < 4; i++)
        op[(size_t)(row + i) * N + col] = acc[rt][ct][i];
    }
}

// ---------------------------------------------------------------------------
// Sum S partials + bias + LeakyReLU. Optional fp32 out (ldo) and bf16 hi/lo
// split planes (stride N) for the next layer's A operand. 128-thr blocks.
// ---------------------------------------------------------------------------
__global__ __launch_bounds__(128) void reduce_ep(
    const float* __restrict__ P, const float* __restrict__ bias,
    float* __restrict__ outF, unsigned short* __restrict__ outHi,
    unsigned short* __restrict__ outLo, int N, int S, int ldo)
{
  const int gid = blockIdx.x * 128 + threadIdx.x;
  const int c4  = N >> 2;
  const int r   = gid / c4;
  const int c   = (gid - r * c4) * 4;
  float4 s = make_float4(0, 0, 0, 0);
  for (int si = 0; si < S; si++) {
    float4 p = *(const float4*)(P + (size_t)si * 128 * N + (size_t)r * N + c);
    s.x += p.x; s.y += p.y; s.z += p.z; s.w += p.w;
  }
  float4 b = *(const float4*)(bias + c);
  s.x = lrelu(s.x + b.x); s.y = lrelu(s.y + b.y);
  s.z = lrelu(s.z + b.z); s.w = lrelu(s.w + b.w);
  if (outF) *(float4*)(outF + (size_t)r * ldo + c) = s;
  if (outHi) {
    ushort4 uh;
    uh.x = (unsigned short)f2bf(s.x); uh.y = (unsigned short)f2bf(s.y);
    uh.z = (unsigned short)f2bf(s.z); uh.w = (unsigned short)f2bf(s.w);
    *(ushort4*)(outHi + (size_t)r * N + c) = uh;
    if (outLo) {
      ushort4 ul;
      ul.x = (unsigned short)f2bf(s.x - bf2f(uh.x));
      ul.y = (unsigned short)f2bf(s.y - bf2f(uh.y));
      ul.z = (unsigned short)f2bf(s.z - bf2f(uh.z));
      ul.w = (unsigned short)f2bf(s.w - bf2f(uh.w));
      *(ushort4*)(outLo + (size_t)r * N + c) = ul;
    }
  }
}

// ---------------------------------------------------------------------------
// gemm4: M = h3(bf16) @ T(fp32->bf16), MFMA 16x16x32, K-split 4.
// Block: 256 thr, tile 128 x 64, 8 k-tiles of 32. Grid (160, 4).
// Asm padded to stride 40 ushorts (kills 8-way bank conflict on A-frag reads).
// Output accM: bf16[4][128][10240] (precision irrelevant: exp(-norm) ~ e^-100s).
// ---------------------------------------------------------------------------
__global__ __launch_bounds__(256, 4) void gemm4_mfma(
    const unsigned short* __restrict__ h3b, const float* __restrict__ T,
    unsigned short* __restrict__ accM)
{
  __shared__ __align__(16) unsigned short Asm[128 * 40]; // [row][k] bf16, padded
  __shared__ __align__(16) unsigned int   Wst[64 * 20];  // [n][kpair]
  const int t     = threadIdx.x;
  const int c0    = blockIdx.x * 64;
  const int kbase = blockIdx.y * 256;
  const int lane  = t & 63, wave = t >> 6;
  const int ml    = lane & 15, q = lane >> 4;
  const int r0    = wave * 32;
  const int ra = t >> 2, qa = t & 3;            // A staging
  const int kp = t & 15, n4 = (t >> 4) * 4;     // T staging

  f32x4 acc[2][4];
  #pragma unroll
  for (int i = 0; i < 2; i++)
    #pragma unroll
    for (int j = 0; j < 4; j++) acc[i][j] = (f32x4){0.f, 0.f, 0.f, 0.f};

  const unsigned short* ap = h3b + (size_t)ra * 1024 + kbase + qa * 8;
  const float*          tp = T + (size_t)(kbase + 2 * kp) * 10240 + c0 + n4;
  uint4  va0 = *(const uint4*)ap;
  uint4  va1 = *(const uint4*)(ap + 64 * 1024);
  float4 vw0 = *(const float4*)tp;
  float4 vw1 = *(const float4*)(tp + 10240);

  for (int kt = 0; kt < 8; kt++) {
    *(uint4*)(Asm + ra * 40 + qa * 8)        = va0;
    *(uint4*)(Asm + (ra + 64) * 40 + qa * 8) = va1;
    Wst[(n4 + 0) * 20 + kp] = f2bf(vw0.x) | (f2bf(vw1.x) << 16);
    Wst[(n4 + 1) * 20 + kp] = f2bf(vw0.y) | (f2bf(vw1.y) << 16);
    Wst[(n4 + 2) * 20 + kp] = f2bf(vw0.z) | (f2bf(vw1.z) << 16);
    Wst[(n4 + 3) * 20 + kp] = f2bf(vw0.w) | (f2bf(vw1.w) << 16);
    __syncthreads();
    if (kt < 7) {                               // prefetch next k-tile
      ap += 32;
      tp += (size_t)32 * 10240;
      va0 = *(const uint4*)ap;
      va1 = *(const uint4*)(ap + 64 * 1024);
      vw0 = *(const float4*)tp;
      vw1 = *(const float4*)(tp + 10240);
    }
    bf16x8 a0 = *(const bf16x8*)(Asm + (r0 + ml) * 40 + q * 8);
    bf16x8 a1 = *(const bf16x8*)(Asm + (r0 + 16 + ml) * 40 + q * 8);
    #pragma unroll
    for (int ct = 0; ct < 4; ct++) {
      bf16x8 b = *(const bf16x8*)((const unsigned short*)Wst +
                                  (size_t)((ct * 16 + ml) * 20 + q * 4) * 2);
      acc[0][ct] = __builtin_amdgcn_mfma_f32_16x16x32_bf16(a0, b, acc[0][ct], 0, 0, 0);
      acc[1][ct] = __builtin_amdgcn_mfma_f32_16x16x32_bf16(a1, b, acc[1][ct], 0, 0, 0);
    }
    __syncthreads();
  }

  // C/D layout: col = lane&15, row = (lane>>4)*4 + reg
  unsigned short* out = accM + (size_t)blockIdx.y * 128 * 10240;
  #pragma unroll
  for (int rt = 0; rt < 2; rt++)
    #pragma unroll
    for (int ct = 0; ct < 4; ct++) {
      int col = c0 + ct * 16 + ml;
      int row = r0 + rt * 16 + q * 4;
      #pragma unroll
      for (int i = 0; i < 4; i++)
        out[(size_t)(row + i) * 10240 + col] = (unsigned short)f2bf(acc[rt][ct][i]);
    }
}

// ---------------------------------------------------------------------------
// pairwise: one block per o (512 blocks x 512 thr = 4 waves/SIMD).
// o_b[j] = sum_i exp(-sum_k |M[i,o,k]-M[j,o,k]|) - 1; M = sum of 4 bf16 splits.
// Thread: 2 j-columns in regs, 16-i strip.
// ---------------------------------------------------------------------------
__global__ __launch_bounds__(512, 4) void pairwise(
    const unsigned short* __restrict__ accM, float* __restrict__ feat)
{
  __shared__ __align__(16) float Ml[128 * 20];
  __shared__ float parts[8 * 128];
  const int t = threadIdx.x;
  const int o = blockIdx.x;
  { // load + combine 4 K-splits: M[:, o, :]
    int i = t >> 2, kh = (t & 3) * 5;
    const unsigned short* p = accM + (size_t)i * 10240 + o * 20 + kh;
    #pragma unroll
    for (int k = 0; k < 5; k++) {
      float s = bf2f(p[k]) + bf2f(p[1310720 + k]) +
                bf2f(p[2621440 + k]) + bf2f(p[3932160 + k]);
      Ml[i * 20 + kh + k] = s;
    }
  }
  __syncthreads();

  const int jg = t & 63, ihalf = t >> 6;   // 64 j-groups x 8 i-strips
  float mj[2][20];
  #pragma unroll
  for (int c = 0; c < 2; c++) {
    const float* src = Ml + (size_t)(jg * 2 + c) * 20;
    #pragma unroll
    for (int k = 0; k < 20; k++) mj[c][k] = src[k];
  }
  float acc[2] = {0.f, 0.f};
  for (int ii = 0; ii < 16; ii++) {
    int i = ihalf * 16 + ii;
    const float4* m4 = (const float4*)(Ml + (size_t)i * 20);
    float mi[20];
    *(float4*)(mi + 0)  = m4[0]; *(float4*)(mi + 4)  = m4[1];
    *(float4*)(mi + 8)  = m4[2]; *(float4*)(mi + 12) = m4[3];
    *(float4*)(mi + 16) = m4[4];
    #pragma unroll
    for (int c = 0; c < 2; c++) {
      float norm = 0.f;
      #pragma unroll
      for (int k = 0; k < 20; k++) norm += fabsf(mi[k] - mj[c][k]);
      acc[c] += __expf(-norm);
    }
  }
  #pragma unroll
  for (int c = 0; c < 2; c++) parts[ihalf * 128 + jg * 2 + c] = acc[c];
  __syncthreads();
  if (t < 128) {
    float s = 0.f;
    #pragma unroll
    for (int ih = 0; ih < 8; ih++) s += parts[ih * 128 + t];
    feat[(size_t)t * 1536 + 1024 + o] = s - 1.0f;   // subtract self-term
  }
}

// ---------------------------------------------------------------------------
// final: out[r] = feat[r,:] . Wc + bc
// ---------------------------------------------------------------------------
__global__ __launch_bounds__(256) void final_dot(
    const float* __restrict__ feat, const float* __restrict__ Wc,
    const float* __restrict__ bc, float* __restrict__ out)
{
  __shared__ float red[4];
  const int t = threadIdx.x, r = blockIdx.x;
  float s = 0.f;
  for (int c = t; c < 1536; c += 256) s += feat[(size_t)r * 1536 + c] * Wc[c];
  for (int off = 32; off > 0; off >>= 1) s += __shfl_down(s, off);
  if ((t & 63) == 0) red[t >> 6] = s;
  __syncthreads();
  if (t == 0) out[r] = red[0] + red[1] + red[2] + red[3] + bc[0];
}

// ---------------------------------------------------------------------------
extern "C" void kernel_launch(void* const* d_in, const int* in_sizes, int n_in,
                              void* d_out, int out_size, void* d_ws, size_t ws_size,
                              hipStream_t stream)
{
  const float* X  = (const float*)d_in[0];
  const float* W1 = (const float*)d_in[1];
  const float* b1 = (const float*)d_in[2];
  const float* W2 = (const float*)d_in[3];
  const float* b2 = (const float*)d_in[4];
  const float* W3 = (const float*)d_in[5];
  const float* b3 = (const float*)d_in[6];
  const float* T  = (const float*)d_in[7];
  const float* Wc = (const float*)d_in[8];
  const float* bc = (const float*)d_in[9];

  char* ws = (char*)d_ws;
  float*          P    = (float*)ws;                  // fp32 partials (<= 8.4MB)
  unsigned short* accB = (unsigned short*)ws;         // bf16[4][128][10240] (after ep3)
  unsigned short* Xhi  = (unsigned short*)(ws + 10485760);
  unsigned short* Xlo  = (unsigned short*)(ws + 11010048);
  unsigned short* h1hi = (unsigned short*)(ws + 11534336);
  unsigned short* h1lo = (unsigned short*)(ws + 12058624);
  unsigned short* h2hi = (unsigned short*)(ws + 12582912);
  unsigned short* h2lo = (unsigned short*)(ws + 12845056);
  unsigned short* h3hi = (unsigned short*)(ws + 13107200);
  float*          feat = (float*)(ws + 13369344);
  float*          out  = (float*)d_out;

  // X -> hi/lo bf16 planes (128x2048)
  convert_split<<<128, 256, 0, stream>>>(X, Xhi, Xlo);
  // layer 1: [128,2048] = lrelu(X @ W1 + b1)   K=2048, S=8
  gemm_mfma3<<<dim3(32, 8), 256, 0, stream>>>(Xhi, Xlo, W1, P, 2048, 2048, 256);
  reduce_ep<<<512, 128, 0, stream>>>(P, b1, nullptr, h1hi, h1lo, 2048, 8, 0);
  // layer 2: [128,1024] = lrelu(h1 @ W2 + b2)  K=2048, S=16
  gemm_mfma3<<<dim3(16, 16), 256, 0, stream>>>(h1hi, h1lo, W2, P, 2048, 1024, 128);
  reduce_ep<<<256, 128, 0, stream>>>(P, b2, nullptr, h2hi, h2lo, 1024, 16, 0);
  // layer 3: [128,1024] = lrelu(h2 @ W3 + b3)  K=1024, S=8 -> feat[:, :1024] + bf16
  gemm_mfma3<<<dim3(16, 8), 256, 0, stream>>>(h2hi, h2lo, W3, P, 1024, 1024, 128);
  reduce_ep<<<256, 128, 0, stream>>>(P, b3, feat, h3hi, nullptr, 1024, 8, 1536);
  // M = h3 @ T  (bf16 MFMA, K-split 4 into bf16 accB)
  gemm4_mfma<<<dim3(160, 4), 256, 0, stream>>>(h3hi, T, accB);
  // minibatch discrimination -> feat[:, 1024:]
  pairwise<<<512, 512, 0, stream>>>(accB, feat);
  // out = feat @ Wc + bc
  final_dot<<<128, 256, 0, stream>>>(feat, Wc, bc, out);
}